// Round 1
// baseline (1186.047 us; speedup 1.0000x reference)
//
#include <hip/hip_runtime.h>

#define NCAM 6
#define DD 118
#define FHH 32
#define FWW 88
#define CC 80
#define NXV 360
#define NYV 360
#define NVOX (NXV * NYV)                      /* 129600 */
#define PTS_PER_CAM (DD * FHH * FWW)          /* 332288 */
#define NPTS (NCAM * PTS_PER_CAM)             /* 1993728 */
#define BLK 256
#define NPT_BLOCKS (NPTS / BLK)               /* 7788, exact */
#define SCAN_BLOCKS ((NVOX + 255) / 256)      /* 507 */
#define SEG 64
#define MAX_SEGS 196608   /* >= 129600 + NPTS/64 = 160752 worst case */

// ws byte offsets
#define WS_P      0
#define WS_CNT    1536
#define WS_NSEG   (WS_CNT + NVOX * 4)
#define WS_CURSOR (WS_NSEG + 16)
#define WS_BSUM   (WS_CURSOR + NVOX * 4)       /* 512 ints */
#define WS_SEGS   (WS_BSUM + 2048)             /* int4 x MAX_SEGS */
#define WS_IDX    (WS_SEGS + MAX_SEGS * 16)    /* NPTS ints */
#define WS_VOXR   (WS_IDX + NPTS * 4)          /* NPTS u32: packed (rank<<17)|vox */

#define VOXR_EMPTY 0xFFFFFFFFu

// inverse of row-major 3x3 in double
__device__ __forceinline__ void inv3x3d(const double* m, double* inv) {
    double c00 = m[4] * m[8] - m[5] * m[7];
    double c01 = m[3] * m[8] - m[5] * m[6];
    double c02 = m[3] * m[7] - m[4] * m[6];
    double det = m[0] * c00 - m[1] * c01 + m[2] * c02;
    double id  = 1.0 / det;
    inv[0] =  c00 * id;
    inv[1] = (m[2] * m[7] - m[1] * m[8]) * id;
    inv[2] = (m[1] * m[5] - m[2] * m[4]) * id;
    inv[3] = -c01 * id;
    inv[4] = (m[0] * m[8] - m[2] * m[6]) * id;
    inv[5] = (m[2] * m[3] - m[0] * m[5]) * id;
    inv[6] =  c02 * id;
    inv[7] = (m[1] * m[6] - m[0] * m[7]) * id;
    inv[8] = (m[0] * m[4] - m[1] * m[3]) * id;
}

__global__ void precomp_kernel(const float* __restrict__ c2e,
                               const float* __restrict__ l2e,
                               const float* __restrict__ intr,
                               const float* __restrict__ aug,
                               const float* __restrict__ laug,
                               float* __restrict__ P) {
    int n = threadIdx.x;
    if (n >= NCAM) return;
    double rots[9], intrins[9], post[9], l2er[9], er[9];
    double trans[3], ptrans[3], l2et[3], et[3];
    for (int i = 0; i < 3; i++) {
        for (int j = 0; j < 3; j++) {
            rots[i * 3 + j]    = c2e[n * 16 + i * 4 + j];
            intrins[i * 3 + j] = intr[n * 16 + i * 4 + j];
            post[i * 3 + j]    = aug[n * 16 + i * 4 + j];
            l2er[i * 3 + j]    = l2e[i * 4 + j];
            er[i * 3 + j]      = laug[i * 4 + j];
        }
        trans[i]  = c2e[n * 16 + i * 4 + 3];
        ptrans[i] = aug[n * 16 + i * 4 + 3];
        l2et[i]   = l2e[i * 4 + 3];
        et[i]     = laug[i * 4 + 3];
    }
    double A[9], IC[9], L[9], Cm[9];
    inv3x3d(post, A);
    inv3x3d(intrins, IC);
    inv3x3d(l2er, L);
    for (int i = 0; i < 3; i++)
        for (int j = 0; j < 3; j++)
            Cm[i * 3 + j] = rots[i * 3 + 0] * IC[0 + j] +
                            rots[i * 3 + 1] * IC[3 + j] +
                            rots[i * 3 + 2] * IC[6 + j];
    float* p = P + n * 48;
    for (int k = 0; k < 9; k++) p[k]      = (float)A[k];
    for (int k = 0; k < 3; k++) p[9 + k]  = (float)ptrans[k];
    for (int k = 0; k < 9; k++) p[12 + k] = (float)Cm[k];
    for (int k = 0; k < 3; k++) p[21 + k] = (float)trans[k];
    for (int k = 0; k < 3; k++) p[24 + k] = (float)l2et[k];
    for (int k = 0; k < 9; k++) p[27 + k] = (float)L[k];
    for (int k = 0; k < 9; k++) p[36 + k] = (float)er[k];
    for (int k = 0; k < 3; k++) p[45 + k] = (float)et[k];
}

// geometry -> voxel id (or -1). Computed exactly ONCE per point now.
__device__ __forceinline__ int point_voxel(const float* __restrict__ P, int gid) {
    int cam   = gid / PTS_PER_CAM;
    int local = gid - cam * PTS_PER_CAM;
    int d   = local / (FHH * FWW);
    int rem = local - d * (FHH * FWW);
    int h   = rem / FWW;
    int w   = rem - h * FWW;
    const float* p = P + cam * 48;

    float fx = (float)((double)w * (703.0 / 87.0));
    float fy = (float)((double)h * (255.0 / 31.0));
    float fd = 1.0f + 0.5f * (float)d;

    float vx = fx - p[9], vy = fy - p[10], vz = fd - p[11];
    float qx = p[0] * vx + p[1] * vy + p[2] * vz;
    float qy = p[3] * vx + p[4] * vy + p[5] * vz;
    float qz = p[6] * vx + p[7] * vy + p[8] * vz;
    float px = qx * qz, py = qy * qz, pz = qz;
    float rx = p[12] * px + p[13] * py + p[14] * pz + p[21];
    float ry = p[15] * px + p[16] * py + p[17] * pz + p[22];
    float rz = p[18] * px + p[19] * py + p[20] * pz + p[23];
    rx -= p[24]; ry -= p[25]; rz -= p[26];
    float sx = p[27] * rx + p[28] * ry + p[29] * rz;
    float sy = p[30] * rx + p[31] * ry + p[32] * rz;
    float sz = p[33] * rx + p[34] * ry + p[35] * rz;
    float gx = p[36] * sx + p[37] * sy + p[38] * sz + p[45];
    float gy = p[39] * sx + p[40] * sy + p[41] * sz + p[46];
    float gz = p[42] * sx + p[43] * sy + p[44] * sz + p[47];

    const float offx = (-54.0f + 0.15f) - 0.15f;
    const float offy = (-54.0f + 0.15f) - 0.15f;
    const float offz = -10.0f;
    int cx = (int)((gx - offx) / 0.3f);
    int cy = (int)((gy - offy) / 0.3f);
    int cz = (int)((gz - offz) / 20.0f);
    bool kept = (cx >= 0) & (cx < NXV) & (cy >= 0) & (cy < NYV) &
                (cz >= 0) & (cz < 1);
    return kept ? (cx * NYV + cy) : -1;
}

// ---- single geometry pass: per-lane atomic count; the atomic's return value
// IS the within-voxel rank, so the fill pass needs no atomics at all.
// Pack vox (17 bits, <131072) | rank<<17 (15 bits; max pts/voxel is a few
// thousand in the ~10m-deep kept frustum, far below 32768).
__global__ __launch_bounds__(BLK) void geom_vox_kernel(
        const float* __restrict__ P, int* __restrict__ cnt,
        unsigned* __restrict__ voxr) {
    int gid = blockIdx.x * BLK + threadIdx.x;
    int vox = point_voxel(P, gid);
    unsigned pr = VOXR_EMPTY;
    if (vox >= 0) {
        int rank = atomicAdd(&cnt[vox], 1);
        pr = (unsigned)vox | ((unsigned)rank << 17);
    }
    voxr[gid] = pr;
}

// ---- exclusive scan of cnt[NVOX] into cursor[NVOX] ----
__global__ __launch_bounds__(256) void scan1_kernel(
        const int* __restrict__ cnt, int* __restrict__ cursor,
        int* __restrict__ bsum) {
    __shared__ int sh[256];
    int tid = threadIdx.x;
    int i = blockIdx.x * 256 + tid;
    int v = (i < NVOX) ? cnt[i] : 0;
    sh[tid] = v;
    __syncthreads();
    for (int o = 1; o < 256; o <<= 1) {
        int t = (tid >= o) ? sh[tid - o] : 0;
        __syncthreads();
        sh[tid] += t;
        __syncthreads();
    }
    int incl = sh[tid];
    if (i < NVOX) cursor[i] = incl - v;
    if (tid == 255) bsum[blockIdx.x] = incl;
}

__global__ __launch_bounds__(512) void scan2_kernel(int* __restrict__ bsum) {
    __shared__ int sh[512];
    int tid = threadIdx.x;
    int v = (tid < SCAN_BLOCKS) ? bsum[tid] : 0;
    sh[tid] = v;
    __syncthreads();
    for (int o = 1; o < 512; o <<= 1) {
        int t = (tid >= o) ? sh[tid - o] : 0;
        __syncthreads();
        sh[tid] += t;
        __syncthreads();
    }
    if (tid < SCAN_BLOCKS) bsum[tid] = sh[tid] - v;  // exclusive
}

// ---- scan3 fused in: finalize cursor, then build segment worklist.
// w-flag: 0 = sole segment of its voxel (plain store), 1 = shared (atomic).
__global__ __launch_bounds__(256) void buildsegs_kernel(
        const int* __restrict__ cnt, int* __restrict__ cursor,
        const int* __restrict__ bsum,
        int* __restrict__ nseg, int4* __restrict__ segs) {
    int v = blockIdx.x * 256 + threadIdx.x;
    if (v >= NVOX) return;
    int off0 = cursor[v] + bsum[blockIdx.x];
    cursor[v] = off0;                         // finalized for fill_kernel
    int c = cnt[v];
    if (c == 0) return;
    int ns = (c + SEG - 1) / SEG;
    int base = atomicAdd(nseg, ns);
    int hv = (c > SEG) ? 1 : 0;
    for (int k = 0; k < ns; k++) {
        if (base + k < MAX_SEGS) {
            int len = min(SEG, c - k * SEG);
            segs[base + k] = make_int4(v, off0 + k * SEG, len, hv);
        }
    }
}

// ---- fill CSR: pure scatter, no geometry recompute, no atomics.
__global__ __launch_bounds__(BLK) void fill_kernel(
        const unsigned* __restrict__ voxr, const int* __restrict__ cursor,
        int* __restrict__ idx) {
    int gid = blockIdx.x * BLK + threadIdx.x;
    unsigned pr = voxr[gid];
    if (pr == VOXR_EMPTY) return;
    int vox  = (int)(pr & 0x1FFFFu);
    int rank = (int)(pr >> 17);
    idx[cursor[vox] + rank] = gid;
}

// ---- gather: grid-stride, one wave per segment; lanes own channels.
// idx for the whole segment loaded once (coalesced), broadcast via shfl.
__global__ __launch_bounds__(256) void gather_kernel(
        const float* __restrict__ feats,
        const int* __restrict__ nseg,
        const int4* __restrict__ segs,
        const int* __restrict__ idx,
        float* __restrict__ out) {
    int lane = threadIdx.x & 63;
    int wid = (blockIdx.x * 256 + threadIdx.x) >> 6;
    int nwaves = gridDim.x * 4;
    int n = *nseg;
    if (n > MAX_SEGS) n = MAX_SEGS;

    for (int s = wid; s < n; s += nwaves) {
        int4 sg = segs[s];
        int vox = sg.x, start = sg.y, len = sg.z, heavy = sg.w;
        int pt_l = (lane < len) ? idx[start + lane] : 0;
        float a0 = 0.f, a1 = 0.f;
        int j = 0;
        for (; j + 4 <= len; j += 4) {
            int p0 = __shfl(pt_l, j);
            int p1 = __shfl(pt_l, j + 1);
            int p2 = __shfl(pt_l, j + 2);
            int p3 = __shfl(pt_l, j + 3);
            const float* r0 = feats + (size_t)p0 * CC;
            const float* r1 = feats + (size_t)p1 * CC;
            const float* r2 = feats + (size_t)p2 * CC;
            const float* r3 = feats + (size_t)p3 * CC;
            float x0 = r0[lane], x1 = r1[lane], x2 = r2[lane], x3 = r3[lane];
            float y0 = 0.f, y1 = 0.f, y2 = 0.f, y3 = 0.f;
            if (lane < 16) {
                y0 = r0[64 + lane]; y1 = r1[64 + lane];
                y2 = r2[64 + lane]; y3 = r3[64 + lane];
            }
            a0 += (x0 + x1) + (x2 + x3);
            a1 += (y0 + y1) + (y2 + y3);
        }
        for (; j < len; ++j) {
            int p0 = __shfl(pt_l, j);
            const float* r0 = feats + (size_t)p0 * CC;
            a0 += r0[lane];
            if (lane < 16) a1 += r0[64 + lane];
        }
        float* o0 = out + (size_t)lane * NVOX + vox;
        float* o1 = out + (size_t)(64 + lane) * NVOX + vox;
        if (heavy) {
            atomicAdd(o0, a0);
            if (lane < 16) atomicAdd(o1, a1);
        } else {
            *o0 = a0;
            if (lane < 16) *o1 = a1;
        }
    }
}

extern "C" void kernel_launch(void* const* d_in, const int* in_sizes, int n_in,
                              void* d_out, int out_size, void* d_ws, size_t ws_size,
                              hipStream_t stream) {
    const float* feats = (const float*)d_in[0];
    const float* c2e   = (const float*)d_in[1];
    const float* l2e   = (const float*)d_in[2];
    const float* intr  = (const float*)d_in[3];
    const float* aug   = (const float*)d_in[4];
    const float* laug  = (const float*)d_in[5];
    float* out = (float*)d_out;

    char* ws = (char*)d_ws;
    float*    P      = (float*)(ws + WS_P);
    int*      cnt    = (int*)(ws + WS_CNT);
    int*      nseg   = (int*)(ws + WS_NSEG);
    int*      cursor = (int*)(ws + WS_CURSOR);
    int*      bsum   = (int*)(ws + WS_BSUM);
    int4*     segs   = (int4*)(ws + WS_SEGS);
    int*      idx    = (int*)(ws + WS_IDX);
    unsigned* voxr   = (unsigned*)(ws + WS_VOXR);

    hipMemsetAsync(cnt, 0, NVOX * 4 + 16, stream);  // cnt + nseg
    hipMemsetAsync(out, 0, (size_t)out_size * sizeof(float), stream);
    precomp_kernel<<<1, 64, 0, stream>>>(c2e, l2e, intr, aug, laug, P);
    geom_vox_kernel<<<NPT_BLOCKS, BLK, 0, stream>>>(P, cnt, voxr);
    scan1_kernel<<<SCAN_BLOCKS, 256, 0, stream>>>(cnt, cursor, bsum);
    scan2_kernel<<<1, 512, 0, stream>>>(bsum);
    buildsegs_kernel<<<SCAN_BLOCKS, 256, 0, stream>>>(cnt, cursor, bsum, nseg, segs);
    fill_kernel<<<NPT_BLOCKS, BLK, 0, stream>>>(voxr, cursor, idx);
    gather_kernel<<<4096, 256, 0, stream>>>(feats, nseg, segs, idx, out);
}